// Round 3
// baseline (401.137 us; speedup 1.0000x reference)
//
#include <hip/hip_runtime.h>

#define NN   8192
#define FIN  512
#define FOUT 64
#define KHALF 4096

typedef __attribute__((ext_vector_type(8)))  short short8;
typedef __attribute__((ext_vector_type(4)))  float floatx4;

__device__ __forceinline__ unsigned f2bf_u(float f) {
  union { float f; unsigned u; } v; v.f = f;
  return (v.u + 0x7fffu + ((v.u >> 16) & 1u)) >> 16;  // RTNE bf16
}
__device__ __forceinline__ unsigned pack2(float a, float b) {
  return f2bf_u(a) | (f2bf_u(b) << 16);
}

// ---------------- Kernel 1: h = inp @ W (bf16 MFMA, fp32 accum) -------------
// Writes hT (bf16 [64][8192] f-major), f1, f2 (fp32). Validated rounds 1-2.
__global__ __launch_bounds__(256) void k1_gemm_h(
    const float* __restrict__ inp, const float* __restrict__ W,
    const float* __restrict__ a,
    float* __restrict__ f1, float* __restrict__ f2,
    unsigned short* __restrict__ hT)
{
  __shared__ unsigned short at[32][72];
  __shared__ unsigned short wt[64][72];
  __shared__ float hsm[32][65];
  __shared__ float alds[2 * FOUT];

  const int tid   = threadIdx.x;
  const int rbase = blockIdx.x * 32;
  if (tid < 2 * FOUT) alds[tid] = a[tid];

  const int lane = tid & 63;
  const int wv   = tid >> 6;
  const int l15  = lane & 15;
  const int q    = lane >> 4;
  const int mi   = wv & 1;
  const int ni0  = (wv >> 1) * 2;

  const int r_a  = tid >> 3;
  const int k8   = (tid & 7) * 8;
  const int n_w  = tid & 63;
  const int kb_w = (tid >> 6) * 16;

  floatx4 acc0 = {0.f, 0.f, 0.f, 0.f};
  floatx4 acc1 = {0.f, 0.f, 0.f, 0.f};

  for (int kk0 = 0; kk0 < FIN; kk0 += 64) {
    __syncthreads();
    const float* ap = inp + (rbase + r_a) * FIN + kk0 + k8;
    float4 v0 = *(const float4*)ap;
    float4 v1 = *(const float4*)(ap + 4);
    *(uint4*)&at[r_a][k8] = make_uint4(pack2(v0.x, v0.y), pack2(v0.z, v0.w),
                                       pack2(v1.x, v1.y), pack2(v1.z, v1.w));
#pragma unroll
    for (int kk2 = 0; kk2 < 16; ++kk2)
      wt[n_w][kb_w + kk2] = (unsigned short)f2bf_u(W[(kk0 + kb_w + kk2) * FOUT + n_w]);
    __syncthreads();
#pragma unroll
    for (int ks = 0; ks < 2; ++ks) {
      short8 af = *(const short8*)&at[mi * 16 + l15][ks * 32 + q * 8];
      short8 b0 = *(const short8*)&wt[ni0 * 16 + l15][ks * 32 + q * 8];
      short8 b1 = *(const short8*)&wt[(ni0 + 1) * 16 + l15][ks * 32 + q * 8];
      acc0 = __builtin_amdgcn_mfma_f32_16x16x32_bf16(af, b0, acc0, 0, 0, 0);
      acc1 = __builtin_amdgcn_mfma_f32_16x16x32_bf16(af, b1, acc1, 0, 0, 0);
    }
  }

  {
    const int m0 = mi * 16 + q * 4;
    const int i0 = rbase + m0;
    {
      const int n = ni0 * 16 + l15;
#pragma unroll
      for (int rg = 0; rg < 4; ++rg) hsm[m0 + rg][n] = acc0[rg];
      *(uint2*)&hT[n * NN + i0] = make_uint2(pack2(acc0[0], acc0[1]),
                                             pack2(acc0[2], acc0[3]));
    }
    {
      const int n = (ni0 + 1) * 16 + l15;
#pragma unroll
      for (int rg = 0; rg < 4; ++rg) hsm[m0 + rg][n] = acc1[rg];
      *(uint2*)&hT[n * NN + i0] = make_uint2(pack2(acc1[0], acc1[1]),
                                             pack2(acc1[2], acc1[3]));
    }
  }
  __syncthreads();
  if (tid < 32) {
    float s1 = 0.f, s2 = 0.f;
#pragma unroll 8
    for (int c = 0; c < FOUT; ++c) {
      float hv = hsm[tid][c];
      s1 += hv * alds[c];
      s2 += hv * alds[FOUT + c];
    }
    f1[rbase + tid] = s1;
    f2[rbase + tid] = s2;
  }
}

// ---------------- Kernel 2: coalesced + pipelined attention partials --------
// 1024 blocks (4/CU): 512 row-groups (16 rows) x 2 K-halves. Per iteration
// (K_TILE=256, 16 iters): coalesced adj load (1KB/row by 16 threads), compute
// w bf16 -> double-buffered LDS, ONE barrier, MFMA with A=w from LDS and
// B=hT fragments straight from L2 (hT is 1MB, L2-resident). Adj prefetched
// 1-deep; 4 blocks/CU hide the barrier's vmcnt drain.
__device__ __forceinline__ uint4 mkw8(const int4 A0, const int4 A1,
                                      const float4 F0, const float4 F1,
                                      const float f1v, float& lsum) {
  float e, w0, w1, w2, w3, w4, w5, w6, w7;
  e = f1v + F0.x; e = fmaxf(e, 0.2f * e); w0 = A0.x ? __expf(e) : 0.f;
  e = f1v + F0.y; e = fmaxf(e, 0.2f * e); w1 = A0.y ? __expf(e) : 0.f;
  e = f1v + F0.z; e = fmaxf(e, 0.2f * e); w2 = A0.z ? __expf(e) : 0.f;
  e = f1v + F0.w; e = fmaxf(e, 0.2f * e); w3 = A0.w ? __expf(e) : 0.f;
  e = f1v + F1.x; e = fmaxf(e, 0.2f * e); w4 = A1.x ? __expf(e) : 0.f;
  e = f1v + F1.y; e = fmaxf(e, 0.2f * e); w5 = A1.y ? __expf(e) : 0.f;
  e = f1v + F1.z; e = fmaxf(e, 0.2f * e); w6 = A1.z ? __expf(e) : 0.f;
  e = f1v + F1.w; e = fmaxf(e, 0.2f * e); w7 = A1.w ? __expf(e) : 0.f;
  lsum += ((w0 + w1) + (w2 + w3)) + ((w4 + w5) + (w6 + w7));
  return make_uint4(pack2(w0, w1), pack2(w2, w3), pack2(w4, w5), pack2(w6, w7));
}

__global__ __launch_bounds__(256, 4) void k2_attn(
    const int* __restrict__ adj,
    const float* __restrict__ f1g, const float* __restrict__ f2g,
    const unsigned short* __restrict__ hT,
    float* __restrict__ part, float* __restrict__ lpart)
{
  __shared__ unsigned short wlds[2][16][264];  // 16.9 KB, row stride 528 B
  __shared__ float pbuf[4][1024];              // 16 KB  (epilogue reduce)
  __shared__ float lred[16][17];

  const int tid   = threadIdx.x;
  const int wv    = tid >> 6;
  const int lane  = tid & 63;
  const int l15   = lane & 15;
  const int q     = lane >> 4;
  const int rbase = (blockIdx.x >> 1) * 16;
  const int kh    = blockIdx.x & 1;
  const int kb    = kh * KHALF;

  const int r = tid >> 4;     // 0..15: attention row
  const int c = tid & 15;     // 16 consecutive j per thread

  const int*   ap = adj + (size_t)(rbase + r) * NN + kb + c * 16;
  const float* fp = f2g + kb + c * 16;
  const float f1v = f1g[rbase + r];

  // B-frag base: lane (l15,q) of wave wv reads hT[ft*16+l15][j0 + q*8 ..+8]
  const unsigned short* hp = hT + (size_t)l15 * NN + kb + wv * 64 + q * 8;

  floatx4 acc[4];
#pragma unroll
  for (int ft = 0; ft < 4; ++ft) acc[ft] = (floatx4){0.f, 0.f, 0.f, 0.f};
  float lsum = 0.f;

  int4 A0 = *(const int4*)(ap);
  int4 A1 = *(const int4*)(ap + 4);
  int4 A2 = *(const int4*)(ap + 8);
  int4 A3 = *(const int4*)(ap + 12);

  for (int it = 0; it < KHALF / 256; ++it) {
    const int nk = (it < KHALF / 256 - 1) ? (it + 1) * 256 : 0;
    int4 nA0 = *(const int4*)(ap + nk);
    int4 nA1 = *(const int4*)(ap + nk + 4);
    int4 nA2 = *(const int4*)(ap + nk + 8);
    int4 nA3 = *(const int4*)(ap + nk + 12);

    const int b = it & 1;
    {
      float4 F0 = *(const float4*)(fp + it * 256);
      float4 F1 = *(const float4*)(fp + it * 256 + 4);
      *(uint4*)&wlds[b][r][c * 16] = mkw8(A0, A1, F0, F1, f1v, lsum);
    }
    {
      float4 F2 = *(const float4*)(fp + it * 256 + 8);
      float4 F3 = *(const float4*)(fp + it * 256 + 12);
      *(uint4*)&wlds[b][r][c * 16 + 8] = mkw8(A2, A3, F2, F3, f1v, lsum);
    }
    __syncthreads();   // wlds[b] ready; writes to wlds[1-b] are fenced by the
                       // NEXT iteration's barrier (double buffer, 1 barrier/it)
    const unsigned short* hit = hp + it * 256;
#pragma unroll
    for (int ks = 0; ks < 2; ++ks) {
      short8 af = *(const short8*)&wlds[b][l15][wv * 64 + ks * 32 + q * 8];
#pragma unroll
      for (int ft = 0; ft < 4; ++ft) {
        short8 bf = *(const short8*)(hit + ks * 32 + (size_t)ft * 16 * NN);
        acc[ft] = __builtin_amdgcn_mfma_f32_16x16x32_bf16(af, bf, acc[ft], 0, 0, 0);
      }
    }
    A0 = nA0; A1 = nA1; A2 = nA2; A3 = nA3;
  }

  // epilogue: stash wave partials, reduce across the 4 k-subsets
  // C-layout: col = lane&15, row = q*4 + rg   (m89-verified)
#pragma unroll
  for (int ft = 0; ft < 4; ++ft)
#pragma unroll
    for (int rg = 0; rg < 4; ++rg)
      pbuf[wv][(q * 4 + rg) * 64 + ft * 16 + l15] = acc[ft][rg];
  lred[r][c] = lsum;
  __syncthreads();

  {
    const int e0 = tid * 4;          // 1024 floats / 256 threads
    const int row = e0 >> 6;
    const int f0 = e0 & 63;
    float4 s0 = *(const float4*)&pbuf[0][e0];
    float4 s1 = *(const float4*)&pbuf[1][e0];
    float4 s2 = *(const float4*)&pbuf[2][e0];
    float4 s3 = *(const float4*)&pbuf[3][e0];
    s0.x += s1.x + s2.x + s3.x; s0.y += s1.y + s2.y + s3.y;
    s0.z += s1.z + s2.z + s3.z; s0.w += s1.w + s2.w + s3.w;
    *(float4*)(part + ((size_t)kh * NN + rbase + row) * 64 + f0) = s0;
  }
  if (tid < 16) {
    float s = 0.f;
#pragma unroll
    for (int i = 0; i < 16; ++i) s += lred[tid][i];
    lpart[(size_t)kh * NN + rbase + tid] = s;
  }
}

// ---------------- Kernel 3: combine k-halves, normalize, ELU ----------------
__global__ __launch_bounds__(256) void k3_combine(
    const float* __restrict__ part, const float* __restrict__ lpart,
    float* __restrict__ out)
{
  const int gid = blockIdx.x * 256 + threadIdx.x;   // 131072 float4s
  const int i = gid >> 4;
  const int c = (gid & 15) * 4;
  const float inv = 1.f / (lpart[i] + lpart[NN + i]);
  float4 p0 = *(const float4*)(part + (size_t)i * 64 + c);
  float4 p1 = *(const float4*)(part + ((size_t)NN + i) * 64 + c);
  float4 v;
  v.x = (p0.x + p1.x) * inv; v.x = (v.x > 0.f) ? v.x : (__expf(v.x) - 1.f);
  v.y = (p0.y + p1.y) * inv; v.y = (v.y > 0.f) ? v.y : (__expf(v.y) - 1.f);
  v.z = (p0.z + p1.z) * inv; v.z = (v.z > 0.f) ? v.z : (__expf(v.z) - 1.f);
  v.w = (p0.w + p1.w) * inv; v.w = (v.w > 0.f) ? v.w : (__expf(v.w) - 1.f);
  *(float4*)(out + (size_t)i * 64 + c) = v;
}

extern "C" void kernel_launch(void* const* d_in, const int* in_sizes, int n_in,
                              void* d_out, int out_size, void* d_ws, size_t ws_size,
                              hipStream_t stream) {
  (void)in_sizes; (void)n_in; (void)out_size; (void)ws_size;
  const float* inp = (const float*)d_in[0];
  const int*   adj = (const int*)d_in[1];
  const float* W   = (const float*)d_in[2];
  const float* a   = (const float*)d_in[3];
  float* out = (float*)d_out;

  float* f1 = (float*)d_ws;                         // 8192
  float* f2 = f1 + NN;                              // 8192
  unsigned short* hT = (unsigned short*)(f2 + NN);  // 64*8192 bf16 = 1 MB
  float* part  = (float*)(hT + (size_t)FOUT * NN);  // 2*8192*64 = 4 MB
  float* lpart = part + 2 * (size_t)NN * FOUT;      // 2*8192

  k1_gemm_h<<<NN / 32, 256, 0, stream>>>(inp, W, a, f1, f2, hT);
  k2_attn<<<(NN / 16) * 2, 256, 0, stream>>>(adj, f1, f2, hT, part, lpart);
  k3_combine<<<NN * FOUT / 4 / 256, 256, 0, stream>>>(part, lpart, out);
}

// Round 4
// 392.653 us; speedup vs baseline: 1.0216x; 1.0216x over previous
//
#include <hip/hip_runtime.h>

#define NN   8192
#define FIN  512
#define FOUT 64
#define KHALF 4096

typedef __attribute__((ext_vector_type(8)))  short short8;
typedef __attribute__((ext_vector_type(4)))  float floatx4;

__device__ __forceinline__ unsigned f2bf_u(float f) {
  union { float f; unsigned u; } v; v.f = f;
  return (v.u + 0x7fffu + ((v.u >> 16) & 1u)) >> 16;  // RTNE bf16
}
__device__ __forceinline__ unsigned pack2(float a, float b) {
  return f2bf_u(a) | (f2bf_u(b) << 16);
}

// ---------------- Kernel 1: h = inp @ W (bf16 MFMA, fp32 accum) -------------
// Writes hT (bf16 [64][8192] f-major), f1, f2 (fp32). Validated rounds 1-3.
__global__ __launch_bounds__(256) void k1_gemm_h(
    const float* __restrict__ inp, const float* __restrict__ W,
    const float* __restrict__ a,
    float* __restrict__ f1, float* __restrict__ f2,
    unsigned short* __restrict__ hT)
{
  __shared__ unsigned short at[32][72];
  __shared__ unsigned short wt[64][72];
  __shared__ float hsm[32][65];
  __shared__ float alds[2 * FOUT];

  const int tid   = threadIdx.x;
  const int rbase = blockIdx.x * 32;
  if (tid < 2 * FOUT) alds[tid] = a[tid];

  const int lane = tid & 63;
  const int wv   = tid >> 6;
  const int l15  = lane & 15;
  const int q    = lane >> 4;
  const int mi   = wv & 1;
  const int ni0  = (wv >> 1) * 2;

  const int r_a  = tid >> 3;
  const int k8   = (tid & 7) * 8;
  const int n_w  = tid & 63;
  const int kb_w = (tid >> 6) * 16;

  floatx4 acc0 = {0.f, 0.f, 0.f, 0.f};
  floatx4 acc1 = {0.f, 0.f, 0.f, 0.f};

  for (int kk0 = 0; kk0 < FIN; kk0 += 64) {
    __syncthreads();
    const float* ap = inp + (rbase + r_a) * FIN + kk0 + k8;
    float4 v0 = *(const float4*)ap;
    float4 v1 = *(const float4*)(ap + 4);
    *(uint4*)&at[r_a][k8] = make_uint4(pack2(v0.x, v0.y), pack2(v0.z, v0.w),
                                       pack2(v1.x, v1.y), pack2(v1.z, v1.w));
#pragma unroll
    for (int kk2 = 0; kk2 < 16; ++kk2)
      wt[n_w][kb_w + kk2] = (unsigned short)f2bf_u(W[(kk0 + kb_w + kk2) * FOUT + n_w]);
    __syncthreads();
#pragma unroll
    for (int ks = 0; ks < 2; ++ks) {
      short8 af = *(const short8*)&at[mi * 16 + l15][ks * 32 + q * 8];
      short8 b0 = *(const short8*)&wt[ni0 * 16 + l15][ks * 32 + q * 8];
      short8 b1 = *(const short8*)&wt[(ni0 + 1) * 16 + l15][ks * 32 + q * 8];
      acc0 = __builtin_amdgcn_mfma_f32_16x16x32_bf16(af, b0, acc0, 0, 0, 0);
      acc1 = __builtin_amdgcn_mfma_f32_16x16x32_bf16(af, b1, acc1, 0, 0, 0);
    }
  }

  {
    const int m0 = mi * 16 + q * 4;
    const int i0 = rbase + m0;
    {
      const int n = ni0 * 16 + l15;
#pragma unroll
      for (int rg = 0; rg < 4; ++rg) hsm[m0 + rg][n] = acc0[rg];
      *(uint2*)&hT[n * NN + i0] = make_uint2(pack2(acc0[0], acc0[1]),
                                             pack2(acc0[2], acc0[3]));
    }
    {
      const int n = (ni0 + 1) * 16 + l15;
#pragma unroll
      for (int rg = 0; rg < 4; ++rg) hsm[m0 + rg][n] = acc1[rg];
      *(uint2*)&hT[n * NN + i0] = make_uint2(pack2(acc1[0], acc1[1]),
                                             pack2(acc1[2], acc1[3]));
    }
  }
  __syncthreads();
  if (tid < 32) {
    float s1 = 0.f, s2 = 0.f;
#pragma unroll 8
    for (int c = 0; c < FOUT; ++c) {
      float hv = hsm[tid][c];
      s1 += hv * alds[c];
      s2 += hv * alds[FOUT + c];
    }
    f1[rbase + tid] = s1;
    f2[rbase + tid] = s2;
  }
}

// ---------------- Kernel 2: attention partials (f2 in LDS, unioned smem) ----
// 1024 blocks (4/CU): 512 row-groups x 2 K-halves. K_TILE=256, double-buffered
// w-tile in LDS, ONE barrier/iter. f2 K-half slice staged in LDS once (kills
// the 16-way-redundant f2 VMEM stream). B=hT fragments direct from L2-resident
// hT (1 MB). adj prefetched 1-deep. Epilogue pbuf aliases wlds/f2lds region
// so LDS stays 34.4 KB -> 4 blocks/CU.
__device__ __forceinline__ uint4 mkw8(const int4 A0, const int4 A1,
                                      const float4 F0, const float4 F1,
                                      const float f1v, float& lsum) {
  float e, w0, w1, w2, w3, w4, w5, w6, w7;
  e = f1v + F0.x; e = fmaxf(e, 0.2f * e); w0 = A0.x ? __expf(e) : 0.f;
  e = f1v + F0.y; e = fmaxf(e, 0.2f * e); w1 = A0.y ? __expf(e) : 0.f;
  e = f1v + F0.z; e = fmaxf(e, 0.2f * e); w2 = A0.z ? __expf(e) : 0.f;
  e = f1v + F0.w; e = fmaxf(e, 0.2f * e); w3 = A0.w ? __expf(e) : 0.f;
  e = f1v + F1.x; e = fmaxf(e, 0.2f * e); w4 = A1.x ? __expf(e) : 0.f;
  e = f1v + F1.y; e = fmaxf(e, 0.2f * e); w5 = A1.y ? __expf(e) : 0.f;
  e = f1v + F1.z; e = fmaxf(e, 0.2f * e); w6 = A1.z ? __expf(e) : 0.f;
  e = f1v + F1.w; e = fmaxf(e, 0.2f * e); w7 = A1.w ? __expf(e) : 0.f;
  lsum += ((w0 + w1) + (w2 + w3)) + ((w4 + w5) + (w6 + w7));
  return make_uint4(pack2(w0, w1), pack2(w2, w3), pack2(w4, w5), pack2(w6, w7));
}

__global__ __launch_bounds__(256, 4) void k2_attn(
    const int* __restrict__ adj,
    const float* __restrict__ f1g, const float* __restrict__ f2g,
    const unsigned short* __restrict__ hT,
    float* __restrict__ part, float* __restrict__ lpart)
{
  // union: [0,16896) wlds[2][16][264] ; [16896,33280) f2lds[4096]
  // epilogue: [0,16384) pbuf[4][1024]
  __shared__ __align__(16) unsigned char smem[33280];
  unsigned short (*wlds)[16][264] = (unsigned short (*)[16][264])smem;
  float* f2lds = (float*)(smem + 16896);
  __shared__ float lred[16][17];

  const int tid   = threadIdx.x;
  const int wv    = tid >> 6;
  const int lane  = tid & 63;
  const int l15   = lane & 15;
  const int q     = lane >> 4;
  const int rbase = (blockIdx.x >> 1) * 16;
  const int kh    = blockIdx.x & 1;
  const int kb    = kh * KHALF;

  const int r = tid >> 4;     // 0..15: attention row
  const int c = tid & 15;     // 16 consecutive j per thread

  // stage f2 K-half slice (4096 floats = 16 KB), fully coalesced
  {
    const float4* src = (const float4*)(f2g + kb) + tid * 4;
    float4* dst = (float4*)f2lds + tid * 4;
    dst[0] = src[0]; dst[1] = src[1]; dst[2] = src[2]; dst[3] = src[3];
  }

  const int* ap  = adj + (size_t)(rbase + r) * NN + kb + c * 16;
  const float f1v = f1g[rbase + r];
  const unsigned short* hp = hT + (size_t)l15 * NN + kb + wv * 64 + q * 8;

  floatx4 acc[4];
#pragma unroll
  for (int ft = 0; ft < 4; ++ft) acc[ft] = (floatx4){0.f, 0.f, 0.f, 0.f};
  float lsum = 0.f;

  int4 A0 = *(const int4*)(ap);
  int4 A1 = *(const int4*)(ap + 4);
  int4 A2 = *(const int4*)(ap + 8);
  int4 A3 = *(const int4*)(ap + 12);

  __syncthreads();   // f2lds ready

  for (int it = 0; it < KHALF / 256; ++it) {
    const int nk = (it < KHALF / 256 - 1) ? (it + 1) * 256 : 0;
    int4 nA0 = *(const int4*)(ap + nk);
    int4 nA1 = *(const int4*)(ap + nk + 4);
    int4 nA2 = *(const int4*)(ap + nk + 8);
    int4 nA3 = *(const int4*)(ap + nk + 12);

    const float* fl = f2lds + it * 256 + c * 16;
    const int b = it & 1;
    {
      float4 F0 = *(const float4*)(fl);
      float4 F1 = *(const float4*)(fl + 4);
      *(uint4*)&wlds[b][r][c * 16] = mkw8(A0, A1, F0, F1, f1v, lsum);
    }
    {
      float4 F2 = *(const float4*)(fl + 8);
      float4 F3 = *(const float4*)(fl + 12);
      *(uint4*)&wlds[b][r][c * 16 + 8] = mkw8(A2, A3, F2, F3, f1v, lsum);
    }
    __syncthreads();   // wlds[b] ready; wlds[1-b] writes fenced by next barrier

    const unsigned short* hit = hp + it * 256;
#pragma unroll
    for (int ks = 0; ks < 2; ++ks) {
      short8 af = *(const short8*)&wlds[b][l15][wv * 64 + ks * 32 + q * 8];
#pragma unroll
      for (int ft = 0; ft < 4; ++ft) {
        short8 bf = *(const short8*)(hit + ks * 32 + (size_t)ft * 16 * NN);
        acc[ft] = __builtin_amdgcn_mfma_f32_16x16x32_bf16(af, bf, acc[ft], 0, 0, 0);
      }
    }
    A0 = nA0; A1 = nA1; A2 = nA2; A3 = nA3;
  }

  __syncthreads();   // retire last MFMA's wlds reads before smem reuse
  float (*pbuf)[1024] = (float (*)[1024])smem;

  // stash wave partials; C-layout: col = lane&15, row = q*4 + rg (m89-verified)
#pragma unroll
  for (int ft = 0; ft < 4; ++ft)
#pragma unroll
    for (int rg = 0; rg < 4; ++rg)
      pbuf[wv][(q * 4 + rg) * 64 + ft * 16 + l15] = acc[ft][rg];
  lred[r][c] = lsum;
  __syncthreads();

  {
    const int e0 = tid * 4;          // 1024 floats / 256 threads
    const int row = e0 >> 6;
    const int f0 = e0 & 63;
    float4 s0 = *(const float4*)&pbuf[0][e0];
    float4 s1 = *(const float4*)&pbuf[1][e0];
    float4 s2 = *(const float4*)&pbuf[2][e0];
    float4 s3 = *(const float4*)&pbuf[3][e0];
    s0.x += s1.x + s2.x + s3.x; s0.y += s1.y + s2.y + s3.y;
    s0.z += s1.z + s2.z + s3.z; s0.w += s1.w + s2.w + s3.w;
    *(float4*)(part + ((size_t)kh * NN + rbase + row) * 64 + f0) = s0;
  }
  if (tid < 16) {
    float s = 0.f;
#pragma unroll
    for (int i = 0; i < 16; ++i) s += lred[tid][i];
    lpart[(size_t)kh * NN + rbase + tid] = s;
  }
}

// ---------------- Kernel 3: combine k-halves, normalize, ELU ----------------
__global__ __launch_bounds__(256) void k3_combine(
    const float* __restrict__ part, const float* __restrict__ lpart,
    float* __restrict__ out)
{
  const int gid = blockIdx.x * 256 + threadIdx.x;   // 131072 float4s
  const int i = gid >> 4;
  const int c = (gid & 15) * 4;
  const float inv = 1.f / (lpart[i] + lpart[NN + i]);
  float4 p0 = *(const float4*)(part + (size_t)i * 64 + c);
  float4 p1 = *(const float4*)(part + ((size_t)NN + i) * 64 + c);
  float4 v;
  v.x = (p0.x + p1.x) * inv; v.x = (v.x > 0.f) ? v.x : (__expf(v.x) - 1.f);
  v.y = (p0.y + p1.y) * inv; v.y = (v.y > 0.f) ? v.y : (__expf(v.y) - 1.f);
  v.z = (p0.z + p1.z) * inv; v.z = (v.z > 0.f) ? v.z : (__expf(v.z) - 1.f);
  v.w = (p0.w + p1.w) * inv; v.w = (v.w > 0.f) ? v.w : (__expf(v.w) - 1.f);
  *(float4*)(out + (size_t)i * 64 + c) = v;
}

extern "C" void kernel_launch(void* const* d_in, const int* in_sizes, int n_in,
                              void* d_out, int out_size, void* d_ws, size_t ws_size,
                              hipStream_t stream) {
  (void)in_sizes; (void)n_in; (void)out_size; (void)ws_size;
  const float* inp = (const float*)d_in[0];
  const int*   adj = (const int*)d_in[1];
  const float* W   = (const float*)d_in[2];
  const float* a   = (const float*)d_in[3];
  float* out = (float*)d_out;

  float* f1 = (float*)d_ws;                         // 8192
  float* f2 = f1 + NN;                              // 8192
  unsigned short* hT = (unsigned short*)(f2 + NN);  // 64*8192 bf16 = 1 MB
  float* part  = (float*)(hT + (size_t)FOUT * NN);  // 2*8192*64 = 4 MB
  float* lpart = part + 2 * (size_t)NN * FOUT;      // 2*8192

  k1_gemm_h<<<NN / 32, 256, 0, stream>>>(inp, W, a, f1, f2, hT);
  k2_attn<<<(NN / 16) * 2, 256, 0, stream>>>(adj, f1, f2, hT, part, lpart);
  k3_combine<<<NN * FOUT / 4 / 256, 256, 0, stream>>>(part, lpart, out);
}

// Round 5
// 392.267 us; speedup vs baseline: 1.0226x; 1.0010x over previous
//
#include <hip/hip_runtime.h>

#define NN   8192
#define FIN  512
#define FOUT 64

typedef __attribute__((ext_vector_type(8)))  short short8;
typedef __attribute__((ext_vector_type(4)))  float floatx4;

__device__ __forceinline__ unsigned f2bf_u(float f) {
  union { float f; unsigned u; } v; v.f = f;
  return (v.u + 0x7fffu + ((v.u >> 16) & 1u)) >> 16;  // RTNE bf16
}
__device__ __forceinline__ unsigned pack2(float a, float b) {
  return f2bf_u(a) | (f2bf_u(b) << 16);
}

// ---------------- Kernel 1: h = inp @ W (bf16 MFMA, fp32 accum) -------------
// Writes hT (bf16 [64][8192] f-major), f1, f2 (fp32). Validated rounds 1-4.
__global__ __launch_bounds__(256) void k1_gemm_h(
    const float* __restrict__ inp, const float* __restrict__ W,
    const float* __restrict__ a,
    float* __restrict__ f1, float* __restrict__ f2,
    unsigned short* __restrict__ hT)
{
  __shared__ unsigned short at[32][72];
  __shared__ unsigned short wt[64][72];
  __shared__ float hsm[32][65];
  __shared__ float alds[2 * FOUT];

  const int tid   = threadIdx.x;
  const int rbase = blockIdx.x * 32;
  if (tid < 2 * FOUT) alds[tid] = a[tid];

  const int lane = tid & 63;
  const int wv   = tid >> 6;
  const int l15  = lane & 15;
  const int q    = lane >> 4;
  const int mi   = wv & 1;
  const int ni0  = (wv >> 1) * 2;

  const int r_a  = tid >> 3;
  const int k8   = (tid & 7) * 8;
  const int n_w  = tid & 63;
  const int kb_w = (tid >> 6) * 16;

  floatx4 acc0 = {0.f, 0.f, 0.f, 0.f};
  floatx4 acc1 = {0.f, 0.f, 0.f, 0.f};

  for (int kk0 = 0; kk0 < FIN; kk0 += 64) {
    __syncthreads();
    const float* ap = inp + (rbase + r_a) * FIN + kk0 + k8;
    float4 v0 = *(const float4*)ap;
    float4 v1 = *(const float4*)(ap + 4);
    *(uint4*)&at[r_a][k8] = make_uint4(pack2(v0.x, v0.y), pack2(v0.z, v0.w),
                                       pack2(v1.x, v1.y), pack2(v1.z, v1.w));
#pragma unroll
    for (int kk2 = 0; kk2 < 16; ++kk2)
      wt[n_w][kb_w + kk2] = (unsigned short)f2bf_u(W[(kk0 + kb_w + kk2) * FOUT + n_w]);
    __syncthreads();
#pragma unroll
    for (int ks = 0; ks < 2; ++ks) {
      short8 af = *(const short8*)&at[mi * 16 + l15][ks * 32 + q * 8];
      short8 b0 = *(const short8*)&wt[ni0 * 16 + l15][ks * 32 + q * 8];
      short8 b1 = *(const short8*)&wt[(ni0 + 1) * 16 + l15][ks * 32 + q * 8];
      acc0 = __builtin_amdgcn_mfma_f32_16x16x32_bf16(af, b0, acc0, 0, 0, 0);
      acc1 = __builtin_amdgcn_mfma_f32_16x16x32_bf16(af, b1, acc1, 0, 0, 0);
    }
  }

  {
    const int m0 = mi * 16 + q * 4;
    const int i0 = rbase + m0;
    {
      const int n = ni0 * 16 + l15;
#pragma unroll
      for (int rg = 0; rg < 4; ++rg) hsm[m0 + rg][n] = acc0[rg];
      *(uint2*)&hT[n * NN + i0] = make_uint2(pack2(acc0[0], acc0[1]),
                                             pack2(acc0[2], acc0[3]));
    }
    {
      const int n = (ni0 + 1) * 16 + l15;
#pragma unroll
      for (int rg = 0; rg < 4; ++rg) hsm[m0 + rg][n] = acc1[rg];
      *(uint2*)&hT[n * NN + i0] = make_uint2(pack2(acc1[0], acc1[1]),
                                             pack2(acc1[2], acc1[3]));
    }
  }
  __syncthreads();
  if (tid < 32) {
    float s1 = 0.f, s2 = 0.f;
#pragma unroll 8
    for (int c = 0; c < FOUT; ++c) {
      float hv = hsm[tid][c];
      s1 += hv * alds[c];
      s2 += hv * alds[FOUT + c];
    }
    f1[rbase + tid] = s1;
    f2[rbase + tid] = s2;
  }
}

// ---------------- Kernel 2: single-pass fused attention ---------------------
// 512 blocks (2/CU), 16 rows/block, FULL K (32 iters of K_TILE=256).
// f2 (32 KB) staged once in LDS; w-tile double-buffered, ONE barrier/iter;
// B-fragments direct from L2-resident hT; adj prefetched 1-deep.
// Epilogue: cross-wave reduce + normalize + ELU -> writes out directly
// (no part/lpart round trip, no combine kernel).
__device__ __forceinline__ uint4 mkw8(const int4 A0, const int4 A1,
                                      const float4 F0, const float4 F1,
                                      const float f1v, float& lsum) {
  float e, w0, w1, w2, w3, w4, w5, w6, w7;
  e = f1v + F0.x; e = fmaxf(e, 0.2f * e); w0 = A0.x ? __expf(e) : 0.f;
  e = f1v + F0.y; e = fmaxf(e, 0.2f * e); w1 = A0.y ? __expf(e) : 0.f;
  e = f1v + F0.z; e = fmaxf(e, 0.2f * e); w2 = A0.z ? __expf(e) : 0.f;
  e = f1v + F0.w; e = fmaxf(e, 0.2f * e); w3 = A0.w ? __expf(e) : 0.f;
  e = f1v + F1.x; e = fmaxf(e, 0.2f * e); w4 = A1.x ? __expf(e) : 0.f;
  e = f1v + F1.y; e = fmaxf(e, 0.2f * e); w5 = A1.y ? __expf(e) : 0.f;
  e = f1v + F1.z; e = fmaxf(e, 0.2f * e); w6 = A1.z ? __expf(e) : 0.f;
  e = f1v + F1.w; e = fmaxf(e, 0.2f * e); w7 = A1.w ? __expf(e) : 0.f;
  lsum += ((w0 + w1) + (w2 + w3)) + ((w4 + w5) + (w6 + w7));
  return make_uint4(pack2(w0, w1), pack2(w2, w3), pack2(w4, w5), pack2(w6, w7));
}

__global__ __launch_bounds__(256, 2) void k2_attn(
    const int* __restrict__ adj,
    const float* __restrict__ f1g, const float* __restrict__ f2g,
    const unsigned short* __restrict__ hT,
    float* __restrict__ out)
{
  // union: [0,16896) wlds[2][16][264] ; [16896,49664) f2lds[8192]
  // epilogue: [0,16384) pbuf[4][1024]
  __shared__ __align__(16) unsigned char smem[49664];
  unsigned short (*wlds)[16][264] = (unsigned short (*)[16][264])smem;
  float* f2lds = (float*)(smem + 16896);
  __shared__ float lred[16][17];
  __shared__ float linv[16];

  const int tid   = threadIdx.x;
  const int wv    = tid >> 6;
  const int lane  = tid & 63;
  const int l15   = lane & 15;
  const int q     = lane >> 4;
  const int rbase = blockIdx.x * 16;

  const int r = tid >> 4;     // 0..15: attention row
  const int c = tid & 15;     // 16 consecutive j per thread

  // stage full f2 (8192 floats = 32 KB), coalesced: 8 float4 per thread
  {
    const float4* src = (const float4*)f2g;
    float4* dst = (float4*)f2lds;
#pragma unroll
    for (int i = 0; i < 8; ++i) dst[tid + i * 256] = src[tid + i * 256];
  }

  const int* ap  = adj + (size_t)(rbase + r) * NN + c * 16;
  const float f1v = f1g[rbase + r];
  const unsigned short* hp = hT + (size_t)l15 * NN + wv * 64 + q * 8;

  floatx4 acc[4];
#pragma unroll
  for (int ft = 0; ft < 4; ++ft) acc[ft] = (floatx4){0.f, 0.f, 0.f, 0.f};
  float lsum = 0.f;

  int4 A0 = *(const int4*)(ap);
  int4 A1 = *(const int4*)(ap + 4);
  int4 A2 = *(const int4*)(ap + 8);
  int4 A3 = *(const int4*)(ap + 12);

  __syncthreads();   // f2lds ready

  for (int it = 0; it < NN / 256; ++it) {
    const int nk = (it < NN / 256 - 1) ? (it + 1) * 256 : 0;
    int4 nA0 = *(const int4*)(ap + nk);
    int4 nA1 = *(const int4*)(ap + nk + 4);
    int4 nA2 = *(const int4*)(ap + nk + 8);
    int4 nA3 = *(const int4*)(ap + nk + 12);

    const float* fl = f2lds + it * 256 + c * 16;
    const int b = it & 1;
    {
      float4 F0 = *(const float4*)(fl);
      float4 F1 = *(const float4*)(fl + 4);
      *(uint4*)&wlds[b][r][c * 16] = mkw8(A0, A1, F0, F1, f1v, lsum);
    }
    {
      float4 F2 = *(const float4*)(fl + 8);
      float4 F3 = *(const float4*)(fl + 12);
      *(uint4*)&wlds[b][r][c * 16 + 8] = mkw8(A2, A3, F2, F3, f1v, lsum);
    }
    __syncthreads();   // wlds[b] ready; wlds[1-b] writes fenced by next barrier

    const unsigned short* hit = hp + it * 256;
#pragma unroll
    for (int ks = 0; ks < 2; ++ks) {
      short8 af = *(const short8*)&wlds[b][l15][wv * 64 + ks * 32 + q * 8];
#pragma unroll
      for (int ft = 0; ft < 4; ++ft) {
        short8 bf = *(const short8*)(hit + ks * 32 + (size_t)ft * 16 * NN);
        acc[ft] = __builtin_amdgcn_mfma_f32_16x16x32_bf16(af, bf, acc[ft], 0, 0, 0);
      }
    }
    A0 = nA0; A1 = nA1; A2 = nA2; A3 = nA3;
  }

  lred[r][c] = lsum;
  __syncthreads();   // retire last MFMA's wlds reads before smem reuse
  float (*pbuf)[1024] = (float (*)[1024])smem;

  // stash wave partials; C-layout: col = lane&15, row = q*4 + rg (m89-verified)
#pragma unroll
  for (int ft = 0; ft < 4; ++ft)
#pragma unroll
    for (int rg = 0; rg < 4; ++rg)
      pbuf[wv][(q * 4 + rg) * 64 + ft * 16 + l15] = acc[ft][rg];
  if (tid < 16) {
    float s = 0.f;
#pragma unroll
    for (int i = 0; i < 16; ++i) s += lred[tid][i];
    linv[tid] = 1.f / s;
  }
  __syncthreads();

  {
    const int e0 = tid * 4;          // 1024 floats / 256 threads
    const int row = e0 >> 6;
    const int f0 = e0 & 63;
    float4 s0 = *(const float4*)&pbuf[0][e0];
    float4 s1 = *(const float4*)&pbuf[1][e0];
    float4 s2 = *(const float4*)&pbuf[2][e0];
    float4 s3 = *(const float4*)&pbuf[3][e0];
    const float inv = linv[row];
    float4 v;
    v.x = (s0.x + s1.x + s2.x + s3.x) * inv;
    v.y = (s0.y + s1.y + s2.y + s3.y) * inv;
    v.z = (s0.z + s1.z + s2.z + s3.z) * inv;
    v.w = (s0.w + s1.w + s2.w + s3.w) * inv;
    v.x = (v.x > 0.f) ? v.x : (__expf(v.x) - 1.f);
    v.y = (v.y > 0.f) ? v.y : (__expf(v.y) - 1.f);
    v.z = (v.z > 0.f) ? v.z : (__expf(v.z) - 1.f);
    v.w = (v.w > 0.f) ? v.w : (__expf(v.w) - 1.f);
    *(float4*)(out + (size_t)(rbase + row) * 64 + f0) = v;
  }
}

extern "C" void kernel_launch(void* const* d_in, const int* in_sizes, int n_in,
                              void* d_out, int out_size, void* d_ws, size_t ws_size,
                              hipStream_t stream) {
  (void)in_sizes; (void)n_in; (void)out_size; (void)ws_size;
  const float* inp = (const float*)d_in[0];
  const int*   adj = (const int*)d_in[1];
  const float* W   = (const float*)d_in[2];
  const float* a   = (const float*)d_in[3];
  float* out = (float*)d_out;

  float* f1 = (float*)d_ws;                         // 8192
  float* f2 = f1 + NN;                              // 8192
  unsigned short* hT = (unsigned short*)(f2 + NN);  // 64*8192 bf16 = 1 MB

  k1_gemm_h<<<NN / 32, 256, 0, stream>>>(inp, W, a, f1, f2, hT);
  k2_attn<<<NN / 16, 256, 0, stream>>>(adj, f1, f2, hT, out);
}